// Round 5
// baseline (121.283 us; speedup 1.0000x reference)
//
#include <hip/hip_runtime.h>
#include <hip/hip_bf16.h>
#include <hip/hip_cooperative_groups.h>

namespace cg = cooperative_groups;

// Problem constants
#define BB 512      // batch
#define FF 1024     // features (= K of GEMM, = NK*KD)
#define NK 64       // num kernels
#define KD 16       // kernel dim

typedef __attribute__((ext_vector_type(4))) float f32x4;
typedef __attribute__((ext_vector_type(8))) short short8;

__device__ __forceinline__ unsigned short bf16_hi(float f) {
    __hip_bfloat16 h = __float2bfloat16(f);   // RNE
    return *reinterpret_cast<unsigned short*>(&h);
}
__device__ __forceinline__ float bf16_back(unsigned short u) {
    __hip_bfloat16 h = *reinterpret_cast<__hip_bfloat16*>(&u);
    return __bfloat162float(h);
}

// ---------------------------------------------------------------------------
// ONE cooperative kernel, grid 256 x 512 (1 block/CU, co-resident):
//   Phase 1: split-bf16 prep (T transpose tiles, x convert, zero out)
//   Phase 2: full-K MFMA GEMM (R4 structure, M2 [kblk][512][16] layout)
//   Phase 3: symmetric pairwise, 9 tile-pair-k units per block
// grid.sync() between phases replaces 2 kernel dispatches (~10 us each).
// ---------------------------------------------------------------------------
__global__ __launch_bounds__(512) void md_fused_kernel(
    const float* __restrict__ x, const float* __restrict__ T,
    unsigned short* __restrict__ xh, unsigned short* __restrict__ xl,
    unsigned short* __restrict__ Th, unsigned short* __restrict__ Tl,
    float* __restrict__ M2, float* __restrict__ out) {
    union Sh {
        float tile[64][65];                         // phase 1: 16.6 KB
        unsigned short glds[2][12288];              // phase 2: 48 KB
        struct {                                    // phase 3: ~30 KB
            float Mi[64][20];
            float Mj[64][16];
            float et[64][65];
            float pr[8][64];
            float pc[8][64];
        } pw;
    };
    __shared__ Sh sh;

    cg::grid_group grid = cg::this_grid();
    const int b = blockIdx.x;
    const int t = threadIdx.x;

    // ===================== Phase 1: prep =====================
    {
        // T transpose: block b owns 64x64 tile (k0, n0)
        const int k0 = (b >> 4) * 64, n0 = (b & 15) * 64;
        #pragma unroll
        for (int rr = 0; rr < 2; ++rr) {
            const int kk = rr * 32 + (t >> 4);
            const float4 v = *(const float4*)&T[(size_t)(k0 + kk) * FF + n0 + (t & 15) * 4];
            sh.tile[kk][(t & 15) * 4 + 0] = v.x; sh.tile[kk][(t & 15) * 4 + 1] = v.y;
            sh.tile[kk][(t & 15) * 4 + 2] = v.z; sh.tile[kk][(t & 15) * 4 + 3] = v.w;
        }
        __syncthreads();
        #pragma unroll
        for (int rr = 0; rr < 2; ++rr) {
            const int nl = rr * 32 + (t >> 4);
            const int kl = (t & 15) * 4;
            ushort4 h, l;
            float f0 = sh.tile[kl + 0][nl], f1 = sh.tile[kl + 1][nl];
            float f2 = sh.tile[kl + 2][nl], f3 = sh.tile[kl + 3][nl];
            h.x = bf16_hi(f0); l.x = bf16_hi(f0 - bf16_back(h.x));
            h.y = bf16_hi(f1); l.y = bf16_hi(f1 - bf16_back(h.y));
            h.z = bf16_hi(f2); l.z = bf16_hi(f2 - bf16_back(h.z));
            h.w = bf16_hi(f3); l.w = bf16_hi(f3 - bf16_back(h.w));
            const size_t o = (size_t)(n0 + nl) * FF + k0 + kl;
            *(ushort4*)&Th[o] = h;
            *(ushort4*)&Tl[o] = l;
        }
        // x conversion: exactly 1 float4 per thread (256*512 = 131072 float4)
        const int idx = b * 512 + t;
        const float4 v = *(const float4*)&x[(size_t)idx * 4];
        ushort4 h, l;
        h.x = bf16_hi(v.x); l.x = bf16_hi(v.x - bf16_back(h.x));
        h.y = bf16_hi(v.y); l.y = bf16_hi(v.y - bf16_back(h.y));
        h.z = bf16_hi(v.z); l.z = bf16_hi(v.z - bf16_back(h.z));
        h.w = bf16_hi(v.w); l.w = bf16_hi(v.w - bf16_back(h.w));
        *(ushort4*)&xh[(size_t)idx * 4] = h;
        *(ushort4*)&xl[(size_t)idx * 4] = l;
        // zero out: 32 float4 per block
        if (t < 32)
            *(float4*)&out[(size_t)(b * 32 + t) * 4] = make_float4(0.f, 0.f, 0.f, 0.f);
    }
    grid.sync();

    // ===================== Phase 2: MFMA GEMM =====================
    {
        const int w = t >> 6, l = t & 63;
        const int xc = b & 7, s = b >> 3;
        const int mt = (xc & 1) * 8 + (s & 7);     // 0..15 (32-row m-tile)
        const int nt = (xc >> 1) * 4 + (s >> 3);   // 0..15 (64-col n-tile)

        const int col16s = (l & 7) ^ (l >> 3);
        const unsigned short* gsrc[3];
        int ldsoff[3];
        #pragma unroll
        for (int j = 0; j < 3; ++j) {
            const int q = w * 3 + j;
            const unsigned short* base; int row0, seg;
            if (q < 4)       { base = xh + (size_t)mt * 32 * FF; row0 = q * 8;        seg = 0;    }
            else if (q < 8)  { base = xl + (size_t)mt * 32 * FF; row0 = (q - 4) * 8;  seg = 2048; }
            else if (q < 16) { base = Th + (size_t)nt * 64 * FF; row0 = (q - 8) * 8;  seg = 4096; }
            else             { base = Tl + (size_t)nt * 64 * FF; row0 = (q - 16) * 8; seg = 8192; }
            gsrc[j] = base + (size_t)(row0 + (l >> 3)) * FF + col16s * 8;
            ldsoff[j] = seg + row0 * 64;
        }

        const int lrow = l & 15, lkg = l >> 4;
        const int ar = (w >> 2) * 16 + lrow;
        const int br = (w & 3) * 16 + lrow;
        const int swa = ar & 7, swb = br & 7;

        f32x4 acc = {};

        #pragma unroll
        for (int j = 0; j < 3; ++j)
            __builtin_amdgcn_global_load_lds(
                (const __attribute__((address_space(1))) void*)gsrc[j],
                (__attribute__((address_space(3))) void*)&sh.glds[0][ldsoff[j]], 16, 0, 0);
        __syncthreads();

        int buf = 0;
        for (int it = 0; it < 16; ++it) {
            if (it < 15) {
                #pragma unroll
                for (int j = 0; j < 3; ++j)
                    __builtin_amdgcn_global_load_lds(
                        (const __attribute__((address_space(1))) void*)(gsrc[j] + (it + 1) * 64),
                        (__attribute__((address_space(3))) void*)&sh.glds[buf ^ 1][ldsoff[j]], 16, 0, 0);
            }
            const unsigned short* L = sh.glds[buf];
            #pragma unroll
            for (int ks = 0; ks < 2; ++ks) {
                const int cb = ks * 4 + lkg;
                const int ca = (cb ^ swa) * 8, cc = (cb ^ swb) * 8;
                short8 ah = *(const short8*)&L[ar * 64 + ca];
                short8 al = *(const short8*)&L[2048 + ar * 64 + ca];
                short8 bh = *(const short8*)&L[4096 + br * 64 + cc];
                short8 bl = *(const short8*)&L[8192 + br * 64 + cc];
                acc = __builtin_amdgcn_mfma_f32_16x16x32_bf16(ah, bh, acc, 0, 0, 0);
                acc = __builtin_amdgcn_mfma_f32_16x16x32_bf16(ah, bl, acc, 0, 0, 0);
                acc = __builtin_amdgcn_mfma_f32_16x16x32_bf16(al, bh, acc, 0, 0, 0);
            }
            __syncthreads();
            buf ^= 1;
        }

        // C/D (m89): col = lane&15, row = (lane>>4)*4 + reg
        const int kblk = nt * 4 + (w & 3);
        const int rowb = mt * 32 + (w >> 2) * 16 + lkg * 4;
        #pragma unroll
        for (int rg = 0; rg < 4; ++rg)
            M2[((size_t)kblk * BB + rowb + rg) * KD + lrow] = acc[rg];
    }
    grid.sync();

    // ===================== Phase 3: symmetric pairwise =====================
    // 2304 units = 256 blocks x 9; unit -> (k, upper-tri tile pair)
    for (int u = 0; u < 9; ++u) {
        const int unit = b * 9 + u;
        const int k = unit & 63;
        int p = unit >> 6;
        int it = 0;
        while (p >= 8 - it) { p -= 8 - it; ++it; }
        const int jt = it + p;
        const bool diag = (it == jt);

        __syncthreads();   // protect LDS reuse across units
        {
            const int tt = t & 255;
            const int row = tt >> 2, dg = (tt & 3) * 4;
            const float* tile = (t < 256)
                ? M2 + ((size_t)k * BB + it * 64) * KD
                : M2 + ((size_t)k * BB + jt * 64) * KD;
            const float4 a = *(const float4*)&tile[tt * 4];
            if (t < 256) *(float4*)&sh.pw.Mi[row][dg] = a;
            else         *(float4*)&sh.pw.Mj[row][dg] = a;
        }
        __syncthreads();

        const int i = t & 63;
        const int wv = t >> 6;              // 0..7 -> j-chunk of 8

        float mi[16];
        #pragma unroll
        for (int dg = 0; dg < 4; ++dg) {
            const float4 v = *(const float4*)&sh.pw.Mi[i][dg * 4];
            mi[dg * 4 + 0] = v.x; mi[dg * 4 + 1] = v.y;
            mi[dg * 4 + 2] = v.z; mi[dg * 4 + 3] = v.w;
        }

        float row_acc = 0.0f;
        #pragma unroll
        for (int jj = 0; jj < 8; ++jj) {
            const int j = wv * 8 + jj;      // wave-uniform -> broadcast reads
            const float4* mj = (const float4*)&sh.pw.Mj[j][0];
            const float4 v0 = mj[0], v1 = mj[1], v2 = mj[2], v3 = mj[3];
            float p0 = (fabsf(mi[0] - v0.x) + fabsf(mi[1] - v0.y)) +
                       (fabsf(mi[2] - v0.z) + fabsf(mi[3] - v0.w));
            float p1 = (fabsf(mi[4] - v1.x) + fabsf(mi[5] - v1.y)) +
                       (fabsf(mi[6] - v1.z) + fabsf(mi[7] - v1.w));
            float p2 = (fabsf(mi[8] - v2.x) + fabsf(mi[9] - v2.y)) +
                       (fabsf(mi[10] - v2.z) + fabsf(mi[11] - v2.w));
            float p3 = (fabsf(mi[12] - v3.x) + fabsf(mi[13] - v3.y)) +
                       (fabsf(mi[14] - v3.z) + fabsf(mi[15] - v3.w));
            const float e = __expf(-((p0 + p1) + (p2 + p3)));
            row_acc += e;
            sh.pw.et[i][j] = e;             // banks (i+j)%32 -> 2-way, free
        }
        sh.pw.pr[wv][i] = row_acc;
        __syncthreads();

        if (!diag) {
            const int j = t & 63;
            const int chunk = t >> 6;       // 0..7 -> ii-chunk of 8
            float col_acc = 0.0f;
            #pragma unroll
            for (int ii = 0; ii < 8; ++ii)
                col_acc += sh.pw.et[chunk * 8 + ii][j];
            sh.pw.pc[chunk][j] = col_acc;
        }
        __syncthreads();

        if (t < 64) {
            float r = ((sh.pw.pr[0][t] + sh.pw.pr[1][t]) + (sh.pw.pr[2][t] + sh.pw.pr[3][t])) +
                      ((sh.pw.pr[4][t] + sh.pw.pr[5][t]) + (sh.pw.pr[6][t] + sh.pw.pr[7][t])) -
                      (diag ? 1.0f : 0.0f);
            atomicAdd(&out[(size_t)(it * 64 + t) * NK + k], r);
        } else if (t < 128 && !diag) {
            const int j = t - 64;
            float c = ((sh.pw.pc[0][j] + sh.pw.pc[1][j]) + (sh.pw.pc[2][j] + sh.pw.pc[3][j])) +
                      ((sh.pw.pc[4][j] + sh.pw.pc[5][j]) + (sh.pw.pc[6][j] + sh.pw.pc[7][j]));
            atomicAdd(&out[(size_t)(jt * 64 + j) * NK + k], c);
        }
    }
}

extern "C" void kernel_launch(void* const* d_in, const int* in_sizes, int n_in,
                              void* d_out, int out_size, void* d_ws, size_t ws_size,
                              hipStream_t stream) {
    const float* x = (const float*)d_in[0];   // [512, 1024] f32
    const float* T = (const float*)d_in[1];   // [1024, 1024] f32
    float* out = (float*)d_out;               // [512, 64] f32

    unsigned short* xh = (unsigned short*)d_ws;         // 512x1024 bf16
    unsigned short* xl = xh + (size_t)BB * FF;
    unsigned short* Th = xl + (size_t)BB * FF;          // 1024x1024 bf16 [n][k]
    unsigned short* Tl = Th + (size_t)FF * FF;
    float* M2 = (float*)(Tl + (size_t)FF * FF);         // [64][512][16] f32

    void* args[] = {(void*)&x, (void*)&T, (void*)&xh, (void*)&xl,
                    (void*)&Th, (void*)&Tl, (void*)&M2, (void*)&out};
    hipLaunchCooperativeKernel((void*)md_fused_kernel, dim3(256), dim3(512),
                               args, 0, stream);
}

// Round 6
// 35.498 us; speedup vs baseline: 3.4166x; 3.4166x over previous
//
#include <hip/hip_runtime.h>
#include <hip/hip_fp16.h>

// Problem constants
#define BB 512      // batch
#define FF 1024     // features (= K of GEMM, = NK*KD)
#define NK 64       // num kernels
#define KD 16       // kernel dim

typedef __attribute__((ext_vector_type(4))) float f32x4;
typedef __attribute__((ext_vector_type(8))) _Float16 half8;

__device__ __forceinline__ unsigned short f16_bits(float f) {
    __half h = __float2half(f);   // RNE
    return *reinterpret_cast<unsigned short*>(&h);
}

// ---------------------------------------------------------------------------
// Prep: blocks 0..255  : T 64x64 transpose tiles -> Tf [n][k] f16
//       blocks 256..383: x -> xf f16 (k-contiguous already)
// Single f16 arrays (was split-bf16 h/l pairs): half the convert + write work.
// ---------------------------------------------------------------------------
__global__ __launch_bounds__(256) void md_prep_kernel(
    const float* __restrict__ x, const float* __restrict__ T,
    unsigned short* __restrict__ xf, unsigned short* __restrict__ Tf) {
    const int b = blockIdx.x;
    const int t = threadIdx.x;
    if (b < 256) {
        __shared__ float tile[64][65];
        const int k0 = (b >> 4) * 64, n0 = (b & 15) * 64;
        #pragma unroll
        for (int rr = 0; rr < 4; ++rr) {
            const int kk = rr * 16 + (t >> 4);
            const float4 v = *(const float4*)&T[(size_t)(k0 + kk) * FF + n0 + (t & 15) * 4];
            tile[kk][(t & 15) * 4 + 0] = v.x; tile[kk][(t & 15) * 4 + 1] = v.y;
            tile[kk][(t & 15) * 4 + 2] = v.z; tile[kk][(t & 15) * 4 + 3] = v.w;
        }
        __syncthreads();
        #pragma unroll
        for (int rr = 0; rr < 4; ++rr) {
            const int nl = rr * 16 + (t >> 4);
            const int kl = (t & 15) * 4;
            ushort4 h;
            h.x = f16_bits(tile[kl + 0][nl]);
            h.y = f16_bits(tile[kl + 1][nl]);
            h.z = f16_bits(tile[kl + 2][nl]);
            h.w = f16_bits(tile[kl + 3][nl]);
            *(ushort4*)&Tf[(size_t)(n0 + nl) * FF + k0 + kl] = h;
        }
    } else {
        const int base = (b - 256) * 256 + t;
        #pragma unroll
        for (int s = 0; s < 4; ++s) {
            const int idx = s * 32768 + base;    // float4 index
            const float4 v = *(const float4*)&x[(size_t)idx * 4];
            ushort4 h;
            h.x = f16_bits(v.x); h.y = f16_bits(v.y);
            h.z = f16_bits(v.z); h.w = f16_bits(v.w);
            *(ushort4*)&xf[(size_t)idx * 4] = h;
        }
    }
}

// ---------------------------------------------------------------------------
// MFMA GEMM, f16 single product, full-K. BM=32, BN=64, BK=64,
// grid 256 blocks (16 mt x 16 nt, XCD-mapped), 512 threads (8 waves).
// Double-buffered LDS (24KB), global_load_lds 16B with pre-swizzled source,
// swizzled ds_read (store c <- global c^(row&7); read c = cb^(row&7)).
// Output M2[kblk][512][16] f32. Blocks 0,1 also zero `out`.
// ---------------------------------------------------------------------------
__global__ __launch_bounds__(512) void md_mfma_kernel(
    const unsigned short* __restrict__ xf, const unsigned short* __restrict__ Tf,
    float* __restrict__ M2, float* __restrict__ out) {
    // per buf (ushort offsets): A @0 (32x64), B @2048 (64x64) = 12KB
    __shared__ __align__(16) unsigned short lds[2][6144];

    const int t = threadIdx.x, w = t >> 6, l = t & 63;
    const int b = blockIdx.x, xc = b & 7, s = b >> 3;
    const int mt = (xc & 1) * 8 + (s & 7);     // 0..15 (32-row m-tile)
    const int nt = (xc >> 1) * 4 + (s >> 3);   // 0..15 (64-col n-tile)

    // zero `out` (128KB) by blocks 0,1 — replaces a memset/prep branch
    if (b < 2) {
        const float4 z = make_float4(0.f, 0.f, 0.f, 0.f);
        #pragma unroll
        for (int q = 0; q < 8; ++q)
            *(float4*)&out[(size_t)(b * 4096 + q * 512 + t) * 4] = z;
    }

    // staging: 12 x 1KB per iter. Wave w(<4): A rows 8w..8w+7; all: B rows 8w..8w+7.
    // LDS gets (row, c) <- global (row, c ^ (row&7)); row&7 == l>>3 here.
    const int col16s = (l & 7) ^ (l >> 3);
    const unsigned short* gA = xf + ((size_t)mt * 32 + (w & 3) * 8 + (l >> 3)) * FF + col16s * 8;
    const unsigned short* gB = Tf + ((size_t)nt * 64 + w * 8 + (l >> 3)) * FF + col16s * 8;
    const int ldsA = (w & 3) * 8 * 64;
    const int ldsB = 2048 + w * 8 * 64;

    const int lrow = l & 15, lkg = l >> 4;
    const int ar = (w >> 2) * 16 + lrow;       // A row 0..31
    const int br = (w & 3) * 16 + lrow;        // B row 0..63
    const int swa = ar & 7, swb = br & 7;

    f32x4 acc = {};

    // prologue: stage buf 0, k-tile 0
    if (w < 4)
        __builtin_amdgcn_global_load_lds(
            (const __attribute__((address_space(1))) void*)gA,
            (__attribute__((address_space(3))) void*)&lds[0][ldsA], 16, 0, 0);
    __builtin_amdgcn_global_load_lds(
        (const __attribute__((address_space(1))) void*)gB,
        (__attribute__((address_space(3))) void*)&lds[0][ldsB], 16, 0, 0);
    __syncthreads();

    int buf = 0;
    for (int it = 0; it < 16; ++it) {
        if (it < 15) {
            const int kt = (it + 1) * 64;
            if (w < 4)
                __builtin_amdgcn_global_load_lds(
                    (const __attribute__((address_space(1))) void*)(gA + kt),
                    (__attribute__((address_space(3))) void*)&lds[buf ^ 1][ldsA], 16, 0, 0);
            __builtin_amdgcn_global_load_lds(
                (const __attribute__((address_space(1))) void*)(gB + kt),
                (__attribute__((address_space(3))) void*)&lds[buf ^ 1][ldsB], 16, 0, 0);
        }
        const unsigned short* L = lds[buf];
        #pragma unroll
        for (int ks = 0; ks < 2; ++ks) {
            const int cb = ks * 4 + lkg;               // k-chunk 0..7
            const half8 a = *(const half8*)&L[ar * 64 + (cb ^ swa) * 8];
            const half8 v = *(const half8*)&L[2048 + br * 64 + (cb ^ swb) * 8];
            acc = __builtin_amdgcn_mfma_f32_16x16x32_f16(a, v, acc, 0, 0, 0);
        }
        __syncthreads();
        buf ^= 1;
    }

    // C/D (m89): col = lane&15, row = (lane>>4)*4 + reg
    const int kblk = nt * 4 + (w & 3);
    const int rowb = mt * 32 + (w >> 2) * 16 + lkg * 4;
    #pragma unroll
    for (int rg = 0; rg < 4; ++rg)
        M2[((size_t)kblk * BB + rowb + rg) * KD + lrow] = acc[rg];
}

// ---------------------------------------------------------------------------
// Symmetric pairwise (R4-verified): M2 [kblk][512][16], each tile one
// contiguous 4KB read. 36 upper-tri tile-pairs x 64 k = 2304 blocks.
// ---------------------------------------------------------------------------
__global__ __launch_bounds__(256) void md_pairwise_sym_kernel(
    const float* __restrict__ M2, float* __restrict__ out) {
    __shared__ float Mi[64][20];
    __shared__ float Mj[64][16];
    __shared__ float et[64][65];
    __shared__ float part_row[4][64];
    __shared__ float part_col[4][64];

    const int bx = blockIdx.x;
    const int k = bx & 63;
    int p = bx >> 6;
    int it = 0;
    while (p >= 8 - it) { p -= 8 - it; ++it; }
    const int jt = it + p;
    const bool diag = (it == jt);
    const int t = threadIdx.x;

    const float* tileI = M2 + ((size_t)k * BB + it * 64) * KD;
    const float* tileJ = M2 + ((size_t)k * BB + jt * 64) * KD;
    {
        const int row = t >> 2, dg = (t & 3) * 4;
        const float4 a = *(const float4*)&tileI[t * 4];
        *(float4*)&Mi[row][dg] = a;
        const float4 c = *(const float4*)&tileJ[t * 4];
        *(float4*)&Mj[row][dg] = c;
    }
    __syncthreads();

    const int i = t & 63;
    const int wv = t >> 6;

    float mi[16];
    #pragma unroll
    for (int dg = 0; dg < 4; ++dg) {
        const float4 v = *(const float4*)&Mi[i][dg * 4];
        mi[dg * 4 + 0] = v.x; mi[dg * 4 + 1] = v.y;
        mi[dg * 4 + 2] = v.z; mi[dg * 4 + 3] = v.w;
    }

    float row_acc = 0.0f;
    #pragma unroll 4
    for (int jj = 0; jj < 16; ++jj) {
        const int j = wv * 16 + jj;      // wave-uniform -> broadcast reads
        const float4* mj = (const float4*)&Mj[j][0];
        const float4 v0 = mj[0], v1 = mj[1], v2 = mj[2], v3 = mj[3];
        float p0 = (fabsf(mi[0] - v0.x) + fabsf(mi[1] - v0.y)) +
                   (fabsf(mi[2] - v0.z) + fabsf(mi[3] - v0.w));
        float p1 = (fabsf(mi[4] - v1.x) + fabsf(mi[5] - v1.y)) +
                   (fabsf(mi[6] - v1.z) + fabsf(mi[7] - v1.w));
        float p2 = (fabsf(mi[8] - v2.x) + fabsf(mi[9] - v2.y)) +
                   (fabsf(mi[10] - v2.z) + fabsf(mi[11] - v2.w));
        float p3 = (fabsf(mi[12] - v3.x) + fabsf(mi[13] - v3.y)) +
                   (fabsf(mi[14] - v3.z) + fabsf(mi[15] - v3.w));
        const float e = __expf(-((p0 + p1) + (p2 + p3)));
        row_acc += e;
        et[i][j] = e;                    // banks (i+j)%32 -> 2-way, free
    }
    part_row[wv][i] = row_acc;
    __syncthreads();

    if (!diag) {
        const int j = t & 63;
        const int chunk = t >> 6;
        float col_acc = 0.0f;
        #pragma unroll
        for (int ii = 0; ii < 16; ++ii)
            col_acc += et[chunk * 16 + ii][j];
        part_col[chunk][j] = col_acc;
    }
    __syncthreads();

    if (t < 64) {
        float r = ((part_row[0][t] + part_row[1][t]) +
                   (part_row[2][t] + part_row[3][t])) - (diag ? 1.0f : 0.0f);
        atomicAdd(&out[(size_t)(it * 64 + t) * NK + k], r);
    } else if (t < 128 && !diag) {
        const int j = t - 64;
        float c = (part_col[0][j] + part_col[1][j]) +
                  (part_col[2][j] + part_col[3][j]);
        atomicAdd(&out[(size_t)(jt * 64 + j) * NK + k], c);
    }
}

extern "C" void kernel_launch(void* const* d_in, const int* in_sizes, int n_in,
                              void* d_out, int out_size, void* d_ws, size_t ws_size,
                              hipStream_t stream) {
    const float* x = (const float*)d_in[0];   // [512, 1024] f32
    const float* T = (const float*)d_in[1];   // [1024, 1024] f32
    float* out = (float*)d_out;               // [512, 64] f32

    unsigned short* xf = (unsigned short*)d_ws;         // 512x1024 f16
    unsigned short* Tf = xf + (size_t)BB * FF;          // 1024x1024 f16 [n][k]
    float* M2 = (float*)(Tf + (size_t)FF * FF);         // [64][512][16] f32

    md_prep_kernel<<<384, 256, 0, stream>>>(x, T, xf, Tf);
    md_mfma_kernel<<<dim3(256), 512, 0, stream>>>(xf, Tf, M2, out);
    md_pairwise_sym_kernel<<<dim3(36 * 64), 256, 0, stream>>>(M2, out);
}